// Round 1
// baseline (244.668 us; speedup 1.0000x reference)
//
#include <hip/hip_runtime.h>
#include <hip/hip_bf16.h>

// Graph Actor Model: encoder MLP -> SGConv(K=2, gcn_norm, no self loops)
// -> 2 dense -> concat -> policy head with row mask.
// N=8192 nodes, Fin=64, hidden=256, Aout=32. All I/O f32.
//
// Strategy:
//  - Single streaming pass over the dense 256 MiB adjacency builds a padded
//    CSC edge list (per-column row indices) + in-degree counts via atomics.
//    This read is the HBM floor (~41 us at 6.3 TB/s).
//  - Propagation done sparsely: out[c,:] = dinv[c]*sum_{r in col(c)} dinv[r]*h[r,:]
//  - Dense layers: f32 tiled LDS GEMM (round 0: correctness-first; ~4.4 GFLOP total).

#define NNODES 8192
#define EPAD   128   // max in-degree storage; Bin(8192, 1/256) max ~55, huge margin

// ---------------- edge build ----------------

__global__ __launch_bounds__(256) void zero_cnt_kernel(int* __restrict__ cnt) {
    int i = blockIdx.x * 256 + threadIdx.x;
    if (i < NNODES) cnt[i] = 0;
}

__global__ __launch_bounds__(256) void build_edges_kernel(
    const float4* __restrict__ adj4, int* __restrict__ cnt, int* __restrict__ edges)
{
    const size_t total = (size_t)NNODES * NNODES / 4;
    const size_t stride = (size_t)gridDim.x * blockDim.x;
    for (size_t i = (size_t)blockIdx.x * blockDim.x + threadIdx.x; i < total; i += stride) {
        float4 v = adj4[i];
        if (v.x != 0.f || v.y != 0.f || v.z != 0.f || v.w != 0.f) {
            size_t base = i * 4;
            int r  = (int)(base / NNODES);
            int c0 = (int)(base % NNODES);
            float vv[4] = {v.x, v.y, v.z, v.w};
            #pragma unroll
            for (int j = 0; j < 4; ++j) {
                if (vv[j] != 0.f) {
                    int c = c0 + j;
                    int slot = atomicAdd(&cnt[c], 1);
                    if (slot < EPAD) edges[(size_t)c * EPAD + slot] = r;
                }
            }
        }
    }
}

__global__ __launch_bounds__(256) void dinv_kernel(const int* __restrict__ cnt,
                                                   float* __restrict__ dinv) {
    int c = blockIdx.x * 256 + threadIdx.x;
    if (c < NNODES) {
        int d = cnt[c];
        dinv[c] = (d > 0) ? rsqrtf((float)d) : 0.f;
    }
}

// ---------------- sparse propagation ----------------
// out[c,f] = dinv[c] * sum_i dinv[edges[c][i]] * h[edges[c][i], f]   (F=256)

__global__ __launch_bounds__(256) void prop_kernel(
    const float* __restrict__ h, const int* __restrict__ cnt,
    const float* __restrict__ dinv, const int* __restrict__ edges,
    float* __restrict__ out)
{
    __shared__ int   se[EPAD];
    __shared__ float sd[EPAD];
    int c = blockIdx.x;
    int t = threadIdx.x;
    int n = cnt[c]; if (n > EPAD) n = EPAD;
    if (t < n) {
        int r = edges[(size_t)c * EPAD + t];
        se[t] = r;
        sd[t] = dinv[r];
    }
    __syncthreads();
    float acc = 0.f;
    for (int i = 0; i < n; ++i) {
        acc += sd[i] * h[(size_t)se[i] * 256 + t];
    }
    out[(size_t)c * 256 + t] = dinv[c] * acc;
}

// ---------------- tiled f32 GEMM ----------------
// C[r,c] = act( sum_k A[r,k] * W[k,c] + bias[c] ) (* mask[r])
// A may be a concat of A1 [N,K1] and A2 [N,K2] (Fc = [Xg, X]).
// BM=64 rows/block, BN cols/block, BK=16; 256 threads, each computes 4 x (BN/16).

template<int K1, int K2, int NOUT, int BN, bool RELU, bool MASK>
__global__ __launch_bounds__(256) void gemm_kernel(
    const float* __restrict__ A1, const float* __restrict__ A2,
    const float* __restrict__ W,  const float* __restrict__ bias,
    float* __restrict__ C, const float* __restrict__ maskv)
{
    constexpr int BM = 64;
    constexpr int BK = 16;
    constexpr int K  = K1 + K2;
    constexpr int TM = 4;         // rows per thread (consecutive)
    constexpr int TN = BN / 16;   // cols per thread (consecutive)

    __shared__ float As[BM][BK + 1];
    __shared__ float Ws[BK][BN];

    const int t  = threadIdx.x;
    const int tx = t % 16;
    const int ty = t / 16;
    const int row0 = blockIdx.x * BM;
    const int col0 = blockIdx.y * BN;

    float acc[TM][TN];
    #pragma unroll
    for (int i = 0; i < TM; ++i)
        #pragma unroll
        for (int j = 0; j < TN; ++j) acc[i][j] = 0.f;

    for (int k0 = 0; k0 < K; k0 += BK) {
        // stage A tile [BM][BK]
        #pragma unroll
        for (int i = 0; i < (BM * BK) / 256; ++i) {
            int idx = t + 256 * i;
            int r  = idx / BK;
            int kk = idx % BK;
            int k  = k0 + kk;
            float v;
            if constexpr (K2 > 0) {
                v = (k < K1) ? A1[(row0 + r) * K1 + k]
                             : A2[(row0 + r) * K2 + (k - K1)];
            } else {
                v = A1[(row0 + r) * K1 + k];
            }
            As[r][kk] = v;
        }
        // stage W tile [BK][BN]
        #pragma unroll
        for (int i = 0; i < (BK * BN) / 256; ++i) {
            int idx = t + 256 * i;
            int kk = idx / BN;
            int c  = idx % BN;
            Ws[kk][c] = W[(k0 + kk) * NOUT + col0 + c];
        }
        __syncthreads();

        #pragma unroll
        for (int kk = 0; kk < BK; ++kk) {
            float a[TM], b[TN];
            #pragma unroll
            for (int i = 0; i < TM; ++i) a[i] = As[ty * TM + i][kk];
            #pragma unroll
            for (int j = 0; j < TN; ++j) b[j] = Ws[kk][tx * TN + j];
            #pragma unroll
            for (int i = 0; i < TM; ++i)
                #pragma unroll
                for (int j = 0; j < TN; ++j) acc[i][j] += a[i] * b[j];
        }
        __syncthreads();
    }

    // epilogue
    #pragma unroll
    for (int i = 0; i < TM; ++i) {
        int r = row0 + ty * TM + i;
        float m = MASK ? maskv[r] : 1.0f;
        #pragma unroll
        for (int j = 0; j < TN; ++j) {
            int c = col0 + tx * TN + j;
            float v = acc[i][j] + bias[c];
            if (RELU) v = fmaxf(v, 0.f);
            if (MASK) v *= m;
            C[(size_t)r * NOUT + c] = v;
        }
    }
}

// ---------------- launch ----------------

extern "C" void kernel_launch(void* const* d_in, const int* in_sizes, int n_in,
                              void* d_out, int out_size, void* d_ws, size_t ws_size,
                              hipStream_t stream) {
    const float* features = (const float*)d_in[0];   // [8192, 64]
    const float* adj      = (const float*)d_in[1];   // [8192, 8192]
    const float* mask     = (const float*)d_in[2];   // [8192]
    const float* W_e1  = (const float*)d_in[3];
    const float* b_e1  = (const float*)d_in[4];
    const float* W_e2  = (const float*)d_in[5];
    const float* b_e2  = (const float*)d_in[6];
    const float* W_gcn = (const float*)d_in[7];
    const float* b_gcn = (const float*)d_in[8];
    const float* W_gd  = (const float*)d_in[9];
    const float* b_gd  = (const float*)d_in[10];
    const float* W_p1  = (const float*)d_in[11];
    const float* b_p1  = (const float*)d_in[12];
    const float* W_p2  = (const float*)d_in[13];
    const float* b_p2  = (const float*)d_in[14];
    const float* W_pi  = (const float*)d_in[15];
    const float* b_pi  = (const float*)d_in[16];
    float* out = (float*)d_out;                      // [8192, 32]

    const int N = NNODES;
    float* ws   = (float*)d_ws;
    float* X    = ws;                        // [N,256] encoder output (kept for concat)
    float* T    = X  + (size_t)N * 256;      // [N,256] scratch
    float* H    = T  + (size_t)N * 256;      // [N,256] scratch
    float* P1   = H  + (size_t)N * 256;      // [N,128]
    float* P2   = P1 + (size_t)N * 128;      // [N,128]
    int*   cnt  = (int*)(P2 + (size_t)N * 128);   // [N]
    float* dinv = (float*)(cnt + N);              // [N]
    int*   edges= (int*)(dinv + N);               // [N][EPAD]
    // total: ~36.1 MiB of d_ws

    // 1) degree + CSC edge list from dense adjacency (the 256 MiB streaming pass)
    zero_cnt_kernel<<<N / 256, 256, 0, stream>>>(cnt);
    build_edges_kernel<<<4096, 256, 0, stream>>>((const float4*)adj, cnt, edges);
    dinv_kernel<<<N / 256, 256, 0, stream>>>(cnt, dinv);

    // 2) encoder MLP: T = relu(feat @ W_e1 + b), X = relu(T @ W_e2 + b)
    gemm_kernel<64, 0, 64, 64, true, false><<<dim3(N / 64, 1), 256, 0, stream>>>(
        features, nullptr, W_e1, b_e1, T, nullptr);
    gemm_kernel<64, 0, 256, 64, true, false><<<dim3(N / 64, 4), 256, 0, stream>>>(
        T, nullptr, W_e2, b_e2, X, nullptr);

    // 3) SGConv K=2: T = prop(X), H = prop(T)
    prop_kernel<<<N, 256, 0, stream>>>(X, cnt, dinv, edges, T);
    prop_kernel<<<N, 256, 0, stream>>>(T, cnt, dinv, edges, H);

    // 4) Xg = relu(H @ W_gcn + b) -> T ; Xg2 = relu(T @ W_gd + b) -> H
    gemm_kernel<256, 0, 256, 64, true, false><<<dim3(N / 64, 4), 256, 0, stream>>>(
        H, nullptr, W_gcn, b_gcn, T, nullptr);
    gemm_kernel<256, 0, 256, 64, true, false><<<dim3(N / 64, 4), 256, 0, stream>>>(
        T, nullptr, W_gd, b_gd, H, nullptr);

    // 5) head: P1 = relu([H|X] @ W_p1 + b), P2 = relu(P1 @ W_p2 + b)
    gemm_kernel<256, 256, 128, 64, true, false><<<dim3(N / 64, 2), 256, 0, stream>>>(
        H, X, W_p1, b_p1, P1, nullptr);
    gemm_kernel<128, 0, 128, 64, true, false><<<dim3(N / 64, 2), 256, 0, stream>>>(
        P1, nullptr, W_p2, b_p2, P2, nullptr);

    // 6) pi = (P2 @ W_pi + b) * mask  -> d_out
    gemm_kernel<128, 0, 32, 32, false, true><<<dim3(N / 64, 1), 256, 0, stream>>>(
        P2, nullptr, W_pi, b_pi, out, mask);
}

// Round 2
// 198.108 us; speedup vs baseline: 1.2350x; 1.2350x over previous
//
#include <hip/hip_runtime.h>
#include <hip/hip_bf16.h>

// Graph Actor Model: encoder MLP -> SGConv(K=2) -> 2 dense -> concat head.
// N=8192, Fin=64, hidden=256, Aout=32. All I/O f32.
//
// R1: GEMMs moved to MFMA 16x16x32 bf16 with split-bf16 (3-product) for
// f32-grade accuracy. LDS holds (hi<<16|lo) packed u32 per element with
// XOR chunk swizzle (T2) for conflict-free ds_read_b128 fragment loads.

#define NNODES 8192
#define EPAD   128

typedef __attribute__((ext_vector_type(8))) short bf16x8;
typedef __attribute__((ext_vector_type(4))) float f32x4;

// ---------------- edge build ----------------

__global__ __launch_bounds__(256) void zero_cnt_kernel(int* __restrict__ cnt) {
    int i = blockIdx.x * 256 + threadIdx.x;
    if (i < NNODES) cnt[i] = 0;
}

__global__ __launch_bounds__(256) void build_edges_kernel(
    const float4* __restrict__ adj4, int* __restrict__ cnt, int* __restrict__ edges)
{
    const size_t total = (size_t)NNODES * NNODES / 4;
    const size_t stride = (size_t)gridDim.x * blockDim.x;
    for (size_t i = (size_t)blockIdx.x * blockDim.x + threadIdx.x; i < total; i += stride) {
        float4 v = adj4[i];
        if (v.x != 0.f || v.y != 0.f || v.z != 0.f || v.w != 0.f) {
            size_t base = i * 4;
            int r  = (int)(base / NNODES);
            int c0 = (int)(base % NNODES);
            float vv[4] = {v.x, v.y, v.z, v.w};
            #pragma unroll
            for (int j = 0; j < 4; ++j) {
                if (vv[j] != 0.f) {
                    int c = c0 + j;
                    int slot = atomicAdd(&cnt[c], 1);
                    if (slot < EPAD) edges[(size_t)c * EPAD + slot] = r;
                }
            }
        }
    }
}

__global__ __launch_bounds__(256) void dinv_kernel(const int* __restrict__ cnt,
                                                   float* __restrict__ dinv) {
    int c = blockIdx.x * 256 + threadIdx.x;
    if (c < NNODES) {
        int d = cnt[c];
        dinv[c] = (d > 0) ? rsqrtf((float)d) : 0.f;
    }
}

// ---------------- sparse propagation ----------------
// out[c,f] = dinv[c] * sum_i dinv[edges[c][i]] * h[edges[c][i], f]   (F=256)

__global__ __launch_bounds__(256) void prop_kernel(
    const float* __restrict__ h, const int* __restrict__ cnt,
    const float* __restrict__ dinv, const int* __restrict__ edges,
    float* __restrict__ out)
{
    __shared__ int   se[EPAD];
    __shared__ float sd[EPAD];
    int c = blockIdx.x;
    int t = threadIdx.x;
    int n = cnt[c]; if (n > EPAD) n = EPAD;
    if (t < n) {
        int r = edges[(size_t)c * EPAD + t];
        se[t] = r;
        sd[t] = dinv[r];
    }
    __syncthreads();
    // 4 independent partial sums to pipeline L2 gather latency
    float a0 = 0.f, a1 = 0.f, a2 = 0.f, a3 = 0.f;
    int i = 0;
    for (; i + 4 <= n; i += 4) {
        a0 += sd[i + 0] * h[(size_t)se[i + 0] * 256 + t];
        a1 += sd[i + 1] * h[(size_t)se[i + 1] * 256 + t];
        a2 += sd[i + 2] * h[(size_t)se[i + 2] * 256 + t];
        a3 += sd[i + 3] * h[(size_t)se[i + 3] * 256 + t];
    }
    for (; i < n; ++i) a0 += sd[i] * h[(size_t)se[i] * 256 + t];
    out[(size_t)c * 256 + t] = dinv[c] * ((a0 + a1) + (a2 + a3));
}

// ---------------- split-bf16 MFMA GEMM ----------------
// y = A @ W, A f32 [N,K] (optionally concat A1|A2), W f32 [K,NOUT].
// Each f32 x split as x ~= hi + lo (both bf16); product via 3 MFMAs:
// Ah*Bh + Ah*Bl + Al*Bh (residual ~2^-18). Packed u32 = (hi16<<16)|lo16.

__device__ inline uint32_t f32_to_split(float v) {
    uint32_t bits = __builtin_bit_cast(uint32_t, v);
    uint32_t hi = (bits + 0x7fffu + ((bits >> 16) & 1u)) & 0xffff0000u;
    float lo = v - __builtin_bit_cast(float, hi);
    uint32_t lob = __builtin_bit_cast(uint32_t, lo);
    uint32_t lo16 = (lob + 0x7fffu + ((lob >> 16) & 1u)) >> 16;
    return hi | lo16;
}

// q0 = packed k..k+3, q1 = packed k+4..k+7 -> hi frag, lo frag (bf16x8).
__device__ inline void unpack_frags(const uint4& q0, const uint4& q1,
                                    bf16x8& hi, bf16x8& lo) {
    union { uint32_t u[4]; bf16x8 v; } H, L;
    H.u[0] = (q0.y & 0xffff0000u) | (q0.x >> 16);
    H.u[1] = (q0.w & 0xffff0000u) | (q0.z >> 16);
    H.u[2] = (q1.y & 0xffff0000u) | (q1.x >> 16);
    H.u[3] = (q1.w & 0xffff0000u) | (q1.z >> 16);
    L.u[0] = (q0.y << 16) | (q0.x & 0xffffu);
    L.u[1] = (q0.w << 16) | (q0.z & 0xffffu);
    L.u[2] = (q1.y << 16) | (q1.x & 0xffffu);
    L.u[3] = (q1.w << 16) | (q1.z & 0xffffu);
    hi = H.v; lo = L.v;
}

template<int K1, int K2, int NOUT, int BM, int BN, int WGM, int WGN, bool RELU, bool MASK>
__global__ __launch_bounds__(256) void mfma_gemm(
    const float* __restrict__ A1, const float* __restrict__ A2,
    const float* __restrict__ W,  const float* __restrict__ bias,
    float* __restrict__ C, const float* __restrict__ maskv)
{
    constexpr int K  = K1 + K2;
    constexpr int BK = 32;                 // k per tile (1 MFMA k-step)
    constexpr int WM = BM / WGM, WN = BN / WGN;
    constexpr int FM = WM / 16,  FN = WN / 16;

    // packed (hi|lo) u32 per element; [rows][BK] with chunk swizzle c^=(r&7)
    __shared__ uint32_t As[BM * BK];
    __shared__ uint32_t Bs[BN * BK];       // W stored transposed: row n, col k

    const int t    = threadIdx.x;
    const int lane = t & 63;
    const int wave = t >> 6;
    const int wm0  = (wave / WGN) * WM;
    const int wn0  = (wave % WGN) * WN;
    const int row0 = blockIdx.x * BM;
    const int col0 = blockIdx.y * BN;
    const int lm   = lane & 15;            // M/N index within 16x16 frag
    const int lk   = lane >> 4;            // k-group: kb = lk*8, chunks lk*2, lk*2+1

    f32x4 acc[FM][FN];
    #pragma unroll
    for (int i = 0; i < FM; ++i)
        #pragma unroll
        for (int j = 0; j < FN; ++j) {
            acc[i][j][0] = 0.f; acc[i][j][1] = 0.f;
            acc[i][j][2] = 0.f; acc[i][j][3] = 0.f;
        }

    for (int k0 = 0; k0 < K; k0 += BK) {
        // ---- stage A: chunks of 4 consecutive k, float4 load + split-pack
        #pragma unroll
        for (int i = 0; i < (BM * BK / 4) / 256; ++i) {
            int ch = t + 256 * i;
            int r  = ch >> 3;              // 8 chunks per row
            int c  = ch & 7;
            int k  = k0 + c * 4;
            float4 v;
            if constexpr (K2 > 0) {
                v = (k < K1) ? *(const float4*)&A1[(size_t)(row0 + r) * K1 + k]
                             : *(const float4*)&A2[(size_t)(row0 + r) * K2 + (k - K1)];
            } else {
                v = *(const float4*)&A1[(size_t)(row0 + r) * K1 + k];
            }
            uint4 q;
            q.x = f32_to_split(v.x); q.y = f32_to_split(v.y);
            q.z = f32_to_split(v.z); q.w = f32_to_split(v.w);
            *(uint4*)&As[r * BK + ((c ^ (r & 7)) << 2)] = q;
        }
        // ---- stage B (transposed): chunk = 4 consecutive k for one col n
        #pragma unroll
        for (int i = 0; i < (BN * BK / 4) / 256; ++i) {
            int ch = t + 256 * i;
            int kc = ch / BN;              // 0..7
            int n  = ch % BN;
            int k  = k0 + kc * 4;
            int col = col0 + n;
            uint4 q;
            q.x = f32_to_split(W[(size_t)(k + 0) * NOUT + col]);
            q.y = f32_to_split(W[(size_t)(k + 1) * NOUT + col]);
            q.z = f32_to_split(W[(size_t)(k + 2) * NOUT + col]);
            q.w = f32_to_split(W[(size_t)(k + 3) * NOUT + col]);
            *(uint4*)&Bs[n * BK + ((kc ^ (n & 7)) << 2)] = q;
        }
        __syncthreads();

        // ---- B fragments for this wave
        uint4 bq[FN][2];
        #pragma unroll
        for (int fn = 0; fn < FN; ++fn) {
            int n = wn0 + fn * 16 + lm;
            bq[fn][0] = *(const uint4*)&Bs[n * BK + (((lk * 2 + 0) ^ (n & 7)) << 2)];
            bq[fn][1] = *(const uint4*)&Bs[n * BK + (((lk * 2 + 1) ^ (n & 7)) << 2)];
        }
        // ---- A fragments + MFMA
        #pragma unroll
        for (int fm = 0; fm < FM; ++fm) {
            int m = wm0 + fm * 16 + lm;
            uint4 a0 = *(const uint4*)&As[m * BK + (((lk * 2 + 0) ^ (m & 7)) << 2)];
            uint4 a1 = *(const uint4*)&As[m * BK + (((lk * 2 + 1) ^ (m & 7)) << 2)];
            bf16x8 ah, al;
            unpack_frags(a0, a1, ah, al);
            #pragma unroll
            for (int fn = 0; fn < FN; ++fn) {
                bf16x8 bh, bl;
                unpack_frags(bq[fn][0], bq[fn][1], bh, bl);
                acc[fm][fn] = __builtin_amdgcn_mfma_f32_16x16x32_bf16(ah, bh, acc[fm][fn], 0, 0, 0);
                acc[fm][fn] = __builtin_amdgcn_mfma_f32_16x16x32_bf16(ah, bl, acc[fm][fn], 0, 0, 0);
                acc[fm][fn] = __builtin_amdgcn_mfma_f32_16x16x32_bf16(al, bh, acc[fm][fn], 0, 0, 0);
            }
        }
        __syncthreads();
    }

    // ---- epilogue: D[m][n]: n = lane&15, m = (lane>>4)*4 + r
    #pragma unroll
    for (int fm = 0; fm < FM; ++fm) {
        #pragma unroll
        for (int fn = 0; fn < FN; ++fn) {
            int col = col0 + wn0 + fn * 16 + lm;
            #pragma unroll
            for (int r = 0; r < 4; ++r) {
                int row = row0 + wm0 + fm * 16 + lk * 4 + r;
                float v = acc[fm][fn][r] + bias[col];
                if (RELU) v = fmaxf(v, 0.f);
                if (MASK) v *= maskv[row];
                C[(size_t)row * NOUT + col] = v;
            }
        }
    }
}

// ---------------- launch ----------------

extern "C" void kernel_launch(void* const* d_in, const int* in_sizes, int n_in,
                              void* d_out, int out_size, void* d_ws, size_t ws_size,
                              hipStream_t stream) {
    const float* features = (const float*)d_in[0];   // [8192, 64]
    const float* adj      = (const float*)d_in[1];   // [8192, 8192]
    const float* mask     = (const float*)d_in[2];   // [8192]
    const float* W_e1  = (const float*)d_in[3];
    const float* b_e1  = (const float*)d_in[4];
    const float* W_e2  = (const float*)d_in[5];
    const float* b_e2  = (const float*)d_in[6];
    const float* W_gcn = (const float*)d_in[7];
    const float* b_gcn = (const float*)d_in[8];
    const float* W_gd  = (const float*)d_in[9];
    const float* b_gd  = (const float*)d_in[10];
    const float* W_p1  = (const float*)d_in[11];
    const float* b_p1  = (const float*)d_in[12];
    const float* W_p2  = (const float*)d_in[13];
    const float* b_p2  = (const float*)d_in[14];
    const float* W_pi  = (const float*)d_in[15];
    const float* b_pi  = (const float*)d_in[16];
    float* out = (float*)d_out;                      // [8192, 32]

    const int N = NNODES;
    float* ws   = (float*)d_ws;
    float* X    = ws;                        // [N,256] encoder output (kept for concat)
    float* T    = X  + (size_t)N * 256;      // [N,256] scratch
    float* H    = T  + (size_t)N * 256;      // [N,256] scratch
    float* P1   = H  + (size_t)N * 256;      // [N,128]
    float* P2   = P1 + (size_t)N * 128;      // [N,128]
    int*   cnt  = (int*)(P2 + (size_t)N * 128);   // [N]
    float* dinv = (float*)(cnt + N);              // [N]
    int*   edges= (int*)(dinv + N);               // [N][EPAD]

    // 1) degree + CSC edge list (256 MiB streaming pass = HBM floor)
    zero_cnt_kernel<<<N / 256, 256, 0, stream>>>(cnt);
    build_edges_kernel<<<4096, 256, 0, stream>>>((const float4*)adj, cnt, edges);
    dinv_kernel<<<N / 256, 256, 0, stream>>>(cnt, dinv);

    // 2) encoder MLP
    mfma_gemm<64, 0, 64, 64, 64, 2, 2, true, false>
        <<<dim3(N / 64, 1), 256, 0, stream>>>(features, nullptr, W_e1, b_e1, T, nullptr);
    mfma_gemm<64, 0, 256, 128, 64, 2, 2, true, false>
        <<<dim3(N / 128, 4), 256, 0, stream>>>(T, nullptr, W_e2, b_e2, X, nullptr);

    // 3) SGConv K=2
    prop_kernel<<<N, 256, 0, stream>>>(X, cnt, dinv, edges, T);
    prop_kernel<<<N, 256, 0, stream>>>(T, cnt, dinv, edges, H);

    // 4) Xg = relu(H @ W_gcn + b) -> T ; Xg2 = relu(T @ W_gd + b) -> H
    mfma_gemm<256, 0, 256, 128, 64, 2, 2, true, false>
        <<<dim3(N / 128, 4), 256, 0, stream>>>(H, nullptr, W_gcn, b_gcn, T, nullptr);
    mfma_gemm<256, 0, 256, 128, 64, 2, 2, true, false>
        <<<dim3(N / 128, 4), 256, 0, stream>>>(T, nullptr, W_gd, b_gd, H, nullptr);

    // 5) head: P1 = relu([H|X] @ W_p1 + b), P2 = relu(P1 @ W_p2 + b)
    mfma_gemm<256, 256, 128, 64, 64, 2, 2, true, false>
        <<<dim3(N / 64, 2), 256, 0, stream>>>(H, X, W_p1, b_p1, P1, nullptr);
    mfma_gemm<128, 0, 128, 64, 64, 2, 2, true, false>
        <<<dim3(N / 64, 2), 256, 0, stream>>>(P1, nullptr, W_p2, b_p2, P2, nullptr);

    // 6) pi = (P2 @ W_pi + b) * mask  -> d_out
    mfma_gemm<128, 0, 32, 64, 32, 2, 2, false, true>
        <<<dim3(N / 64, 1), 256, 0, stream>>>(P2, nullptr, W_pi, b_pi, out, mask);
}